// Round 1
// baseline (1734.803 us; speedup 1.0000x reference)
//
#include <hip/hip_runtime.h>

typedef unsigned short u16;
typedef __bf16 bf16x8 __attribute__((ext_vector_type(8)));
typedef float f32x4 __attribute__((ext_vector_type(4)));
typedef unsigned short u16x4 __attribute__((ext_vector_type(4)));
typedef unsigned int u32x4 __attribute__((ext_vector_type(4)));

#define NA 2048
#define NT 91
#define ND 256
#define NM (NA*NT)   // 186368, divisible by 128

__device__ __forceinline__ u16 f2bf(float f) {
  union { float f; unsigned u; } v; v.f = f;
  unsigned r = v.u + 0x7FFFu + ((v.u >> 16) & 1u);   // RNE
  return (u16)(r >> 16);
}

__device__ __forceinline__ f32x4 mfma16(bf16x8 a, bf16x8 b, f32x4 c) {
  return __builtin_amdgcn_mfma_f32_16x16x32_bf16(a, b, c, 0, 0, 0);
}

// ---------------------------------------------------------------------------
// k_prep: weights -> bf16, transposed to [out][in] so B-fragments read 8
// contiguous k elements. wqkvT rows: 0-255 = W_K cols, 256-511 = W_V, 512-767 = W_Q0.
// ---------------------------------------------------------------------------
__global__ __launch_bounds__(256) void k_prep(
    const float* __restrict__ W_K, const float* __restrict__ W_V,
    const float* __restrict__ W_Q0, const float* __restrict__ W_Y2,
    const float* __restrict__ W_F1, const float* __restrict__ W_F2,
    u16* __restrict__ wqkvT, u16* __restrict__ wy2T,
    u16* __restrict__ wf1T, u16* __restrict__ wf2T)
{
  int e = blockIdx.x * 256 + threadIdx.x;   // 786432 total
  if (e < 196608) {
    int n = e >> 8, k = e & 255;
    int sel = n >> 8, nl = n & 255;
    const float* W = sel == 0 ? W_K : (sel == 1 ? W_V : W_Q0);
    wqkvT[e] = f2bf(W[k * 256 + nl]);
  } else if (e < 262144) {
    int i = e - 196608; int n = i >> 8, k = i & 255;
    wy2T[i] = f2bf(W_Y2[k * 256 + n]);
  } else if (e < 524288) {
    int i = e - 262144; int n = i >> 8, k = i & 255;   // n<1024
    wf1T[i] = f2bf(W_F1[k * 1024 + n]);
  } else {
    int i = e - 524288; int n = i >> 10, k = i & 1023; // n<256
    wf2T[i] = f2bf(W_F2[k * 256 + n]);
  }
}

// ---------------------------------------------------------------------------
// k_qkv: C[M x 768] = relu(X @ [W_K|W_V|W_Q0] + b), scale Q part, scatter to
// Qp/Kp/Vp in (A,H,T,DH) layout. 128x128 tiles, BK=64, 4 waves (2x2 of 64x64).
// ---------------------------------------------------------------------------
__global__ __launch_bounds__(256) void k_qkv(
    const float* __restrict__ x, const u16* __restrict__ wqkvT,
    const float* __restrict__ bK, const float* __restrict__ bV,
    const float* __restrict__ bQ, const float* __restrict__ sq,
    float* __restrict__ outQ, float* __restrict__ outK, float* __restrict__ outV)
{
  __shared__ __align__(16) u16 lx[128 * 64];
  __shared__ __align__(16) u16 lw[128 * 64];
  const int tid = threadIdx.x, lane = tid & 63, wave = tid >> 6;
  const int bm = blockIdx.x / 6, bn = blockIdx.x % 6;
  const int m0 = bm * 128, n0 = bn * 128;
  const int wm = (wave >> 1) * 64, wn = (wave & 1) * 64;
  const f32x4 z4 = {0.f, 0.f, 0.f, 0.f};

  f32x4 acc[4][4];
  #pragma unroll
  for (int i = 0; i < 4; ++i)
    #pragma unroll
    for (int j = 0; j < 4; ++j) acc[i][j] = z4;

  for (int kk = 0; kk < 256; kk += 64) {
    #pragma unroll
    for (int it = 0; it < 8; ++it) {             // X tile: 128x64 f32->bf16
      int ch = tid + it * 256;                   // 2048 chunks of 4
      int row = ch >> 4, col4 = (ch & 15) * 4;
      f32x4 v = *(const f32x4*)&x[(size_t)(m0 + row) * 256 + kk + col4];
      u16x4 o;
      o[0] = f2bf(v[0]); o[1] = f2bf(v[1]); o[2] = f2bf(v[2]); o[3] = f2bf(v[3]);
      *(u16x4*)&lx[row * 64 + (col4 ^ ((row & 7) << 3))] = o;
    }
    #pragma unroll
    for (int it = 0; it < 4; ++it) {             // W tile: 128x64 bf16
      int ch = tid + it * 256;                   // 1024 chunks of 8
      int row = ch >> 3, col8 = (ch & 7) * 8;
      u32x4 v = *(const u32x4*)&wqkvT[(size_t)(n0 + row) * 256 + kk + col8];
      *(u32x4*)&lw[row * 64 + (col8 ^ ((row & 7) << 3))] = v;
    }
    __syncthreads();
    #pragma unroll
    for (int ks = 0; ks < 2; ++ks) {
      int k = ks * 32 + (lane >> 4) * 8;
      bf16x8 af[4], bg[4];
      #pragma unroll
      for (int mt = 0; mt < 4; ++mt) {
        int r = wm + mt * 16 + (lane & 15);
        af[mt] = *(const bf16x8*)&lx[r * 64 + (k ^ ((r & 7) << 3))];
      }
      #pragma unroll
      for (int nt = 0; nt < 4; ++nt) {
        int r = wn + nt * 16 + (lane & 15);
        bg[nt] = *(const bf16x8*)&lw[r * 64 + (k ^ ((r & 7) << 3))];
      }
      #pragma unroll
      for (int mt = 0; mt < 4; ++mt)
        #pragma unroll
        for (int nt = 0; nt < 4; ++nt)
          acc[mt][nt] = mfma16(af[mt], bg[nt], acc[mt][nt]);
    }
    __syncthreads();
  }

  #pragma unroll
  for (int mt = 0; mt < 4; ++mt)
    #pragma unroll
    for (int j = 0; j < 4; ++j) {
      unsigned grow = m0 + wm + mt * 16 + (lane >> 4) * 4 + j;
      unsigned a = grow / 91u;
      unsigned t = grow - a * 91u;
      #pragma unroll
      for (int nt = 0; nt < 4; ++nt) {
        int gcol = n0 + wn + nt * 16 + (lane & 15);
        int which = gcol >> 8;      // 0=K,1=V,2=Q
        int dl = gcol & 255;
        int h = dl >> 6, dh = dl & 63;
        float v = acc[mt][nt][j];
        v += (which == 0 ? bK[dl] : which == 1 ? bV[dl] : bQ[dl]);
        v = fmaxf(v, 0.f);
        if (which == 2) v *= sq[dh];
        float* dst = which == 0 ? outK : which == 1 ? outV : outQ;
        dst[(size_t)((a * 4u + h) * 91u + t) * 64u + dh] = v;
      }
    }
}

// ---------------------------------------------------------------------------
// k_attn: one block per (a,h). 384 threads = 6 waves, wave = 16-row m-tile.
// E = (Q K^T)/2 masked, softmax, Y1 = P V -> ws (bf16, (A,T,D) layout).
// ---------------------------------------------------------------------------
__global__ __launch_bounds__(384) void k_attn(
    const float* __restrict__ Qp, const float* __restrict__ Kp,
    const float* __restrict__ Vp, const void* __restrict__ pmask,
    u16* __restrict__ y1)
{
  __shared__ __align__(16) u16 lq[96 * 64];
  __shared__ __align__(16) u16 lk[96 * 64];
  __shared__ __align__(16) u16 lvT[64 * 104];   // [dh][key], stride 104
  __shared__ __align__(16) u16 lp[96 * 104];    // [q][key],  stride 104
  __shared__ float pm[96];
  __shared__ int is4_s;

  const int tid = threadIdx.x, lane = tid & 63, wave = tid >> 6;
  const int ah = blockIdx.x, a = ah >> 2, h = ah & 3;
  const size_t base = (size_t)ah * 91 * 64;
  const f32x4 z4 = {0.f, 0.f, 0.f, 0.f};

  if (tid == 0) {  // detect 1-byte vs 4-byte mask elements (byte pos 1 mod 4)
    const unsigned* pw = (const unsigned*)pmask;
    unsigned accm = 0;
    for (int i = 0; i < 64; ++i) accm |= pw[i] & 0x0000FF00u;
    is4_s = (accm == 0) ? 1 : 0;
  }
  __syncthreads();
  const int is4 = is4_s;
  if (tid < 96) {
    float v = 0.f;
    if (tid < 91) {
      int gi = a * 91 + tid;
      if (is4) v = (((const unsigned*)pmask)[gi] != 0) ? 1.f : 0.f;
      else     v = (((const unsigned char*)pmask)[gi] != 0) ? 1.f : 0.f;
    }
    pm[tid] = v;
  }

  for (int ch = tid; ch < 1536; ch += 384) {     // stage Q,K (96x64, pad 0)
    int row = ch >> 4, col4 = (ch & 15) * 4;
    f32x4 vq = z4, vk = z4;
    if (row < 91) {
      vq = *(const f32x4*)&Qp[base + (size_t)row * 64 + col4];
      vk = *(const f32x4*)&Kp[base + (size_t)row * 64 + col4];
    }
    u16x4 oq, ok;
    #pragma unroll
    for (int i = 0; i < 4; ++i) { oq[i] = f2bf(vq[i]); ok[i] = f2bf(vk[i]); }
    int idx = row * 64 + (col4 ^ ((row & 7) << 3));
    *(u16x4*)&lq[idx] = oq;
    *(u16x4*)&lk[idx] = ok;
  }
  for (int ch = tid; ch < 1536; ch += 384) {     // stage V transposed
    int row = ch >> 4, col4 = (ch & 15) * 4;
    f32x4 vv = z4;
    if (row < 91) vv = *(const f32x4*)&Vp[base + (size_t)row * 64 + col4];
    #pragma unroll
    for (int i = 0; i < 4; ++i) lvT[(col4 + i) * 104 + row] = f2bf(vv[i]);
  }
  __syncthreads();

  // E = Q K^T (wave's 16 q-rows x 96 keys)
  f32x4 e[6];
  #pragma unroll
  for (int nt = 0; nt < 6; ++nt) e[nt] = z4;
  #pragma unroll
  for (int ks = 0; ks < 2; ++ks) {
    int k = ks * 32 + (lane >> 4) * 8;
    int rq = wave * 16 + (lane & 15);
    bf16x8 aq = *(const bf16x8*)&lq[rq * 64 + (k ^ ((rq & 7) << 3))];
    #pragma unroll
    for (int nt = 0; nt < 6; ++nt) {
      int rk = nt * 16 + (lane & 15);
      bf16x8 bk8 = *(const bf16x8*)&lk[rk * 64 + (k ^ ((rk & 7) << 3))];
      e[nt] = mfma16(aq, bk8, e[nt]);
    }
  }

  // mask + softmax (row lives in a 16-lane group), write P (bf16)
  #pragma unroll
  for (int j = 0; j < 4; ++j) {
    int q = wave * 16 + (lane >> 4) * 4 + j;
    float pmq = pm[q];
    float ev[6];
    float mx = -3e38f;
    #pragma unroll
    for (int nt = 0; nt < 6; ++nt) {
      int col = nt * 16 + (lane & 15);
      float val;
      if (col >= 91)                         val = -1e30f;   // LDS pad: vanish
      else if (pmq == 0.f || pm[col] == 0.f) val = -1e10f;   // ref semantics
      else                                   val = 0.5f * e[nt][j];
      ev[nt] = val;
      mx = fmaxf(mx, val);
    }
    #pragma unroll
    for (int s = 1; s < 16; s <<= 1) mx = fmaxf(mx, __shfl_xor(mx, s));
    float sum = 0.f;
    #pragma unroll
    for (int nt = 0; nt < 6; ++nt) { ev[nt] = __expf(ev[nt] - mx); sum += ev[nt]; }
    #pragma unroll
    for (int s = 1; s < 16; s <<= 1) sum += __shfl_xor(sum, s);
    float rs = 1.f / sum;
    #pragma unroll
    for (int nt = 0; nt < 6; ++nt)
      lp[q * 104 + nt * 16 + (lane & 15)] = f2bf(ev[nt] * rs);
  }
  __syncthreads();

  // Y1 = P V
  f32x4 y[4];
  #pragma unroll
  for (int nt = 0; nt < 4; ++nt) y[nt] = z4;
  #pragma unroll
  for (int kt = 0; kt < 3; ++kt) {
    int k = kt * 32 + (lane >> 4) * 8;
    int rq = wave * 16 + (lane & 15);
    bf16x8 ap = *(const bf16x8*)&lp[rq * 104 + k];
    #pragma unroll
    for (int nt = 0; nt < 4; ++nt) {
      bf16x8 bv = *(const bf16x8*)&lvT[(nt * 16 + (lane & 15)) * 104 + k];
      y[nt] = mfma16(ap, bv, y[nt]);
    }
  }
  #pragma unroll
  for (int j = 0; j < 4; ++j) {
    int q = wave * 16 + (lane >> 4) * 4 + j;
    if (q < 91) {
      size_t rbase = ((size_t)a * 91 + q) * 256 + h * 64;
      #pragma unroll
      for (int nt = 0; nt < 4; ++nt)
        y1[rbase + nt * 16 + (lane & 15)] = f2bf(y[nt][j]);
    }
  }
}

// ---------------------------------------------------------------------------
// k_ffn: per 64-row block: S = relu(Y1@Wy2+b)+x ; F1=relu(S@Wf1+b) chunked;
// F2 += F1c@Wf2c ; relu+bias ; LayerNorm ; write Z.
// ---------------------------------------------------------------------------
__global__ __launch_bounds__(256) void k_ffn(
    const u16* __restrict__ y1, const float* __restrict__ x,
    const u16* __restrict__ wy2T, const float* __restrict__ by2,
    const u16* __restrict__ wf1T, const float* __restrict__ bF1,
    const u16* __restrict__ wf2T, const float* __restrict__ bF2,
    const float* __restrict__ lng, const float* __restrict__ lnb,
    float* __restrict__ z)
{
  __shared__ __align__(16) char BUF[74240];
  u16* sA  = (u16*)BUF;                 // [64][256] bf16 swz15 (Y1 then S)
  u16* sC  = (u16*)(BUF + 32768);       // weight staging (32 KB)
  u16* sF1 = (u16*)(BUF + 65536);       // [64][64] bf16 swz7
  float* F2L = (float*)BUF;             // phase 3: [64][260] f32
  float* muL = (float*)(BUF + 73728);
  float* rsL = (float*)(BUF + 73984);

  const int tid = threadIdx.x, lane = tid & 63, w = tid >> 6;
  const int m0 = blockIdx.x * 64;
  const f32x4 z4 = {0.f, 0.f, 0.f, 0.f};

  #pragma unroll
  for (int it = 0; it < 8; ++it) {               // stage Y1 tile
    int ch = tid + it * 256;
    int row = ch >> 5, col8 = (ch & 31) * 8;
    u32x4 v = *(const u32x4*)&y1[(size_t)(m0 + row) * 256 + col8];
    *(u32x4*)&sA[row * 256 + (col8 ^ ((row & 15) << 3))] = v;
  }
  __syncthreads();

  // ---- phase 1: Y2 + residual -> S (into sA) ----
  f32x4 acc[4][4];
  #pragma unroll
  for (int i = 0; i < 4; ++i)
    #pragma unroll
    for (int j = 0; j < 4; ++j) acc[i][j] = z4;

  for (int kk = 0; kk < 256; kk += 64) {
    #pragma unroll
    for (int it = 0; it < 8; ++it) {             // Wy2T [256 n][64 k]
      int ch = tid + it * 256;
      int row = ch >> 3, col8 = (ch & 7) * 8;
      u32x4 v = *(const u32x4*)&wy2T[(size_t)row * 256 + kk + col8];
      *(u32x4*)&sC[row * 64 + (col8 ^ ((row & 7) << 3))] = v;
    }
    __syncthreads();
    #pragma unroll
    for (int ks = 0; ks < 2; ++ks) {
      int k = ks * 32 + (lane >> 4) * 8;
      bf16x8 af[4], bg[4];
      #pragma unroll
      for (int mt = 0; mt < 4; ++mt) {
        int r = mt * 16 + (lane & 15);
        af[mt] = *(const bf16x8*)&sA[r * 256 + ((kk + k) ^ ((r & 15) << 3))];
      }
      #pragma unroll
      for (int nt = 0; nt < 4; ++nt) {
        int r = w * 64 + nt * 16 + (lane & 15);
        bg[nt] = *(const bf16x8*)&sC[r * 64 + (k ^ ((r & 7) << 3))];
      }
      #pragma unroll
      for (int mt = 0; mt < 4; ++mt)
        #pragma unroll
        for (int nt = 0; nt < 4; ++nt)
          acc[mt][nt] = mfma16(af[mt], bg[nt], acc[mt][nt]);
    }
    __syncthreads();
  }
  #pragma unroll
  for (int mt = 0; mt < 4; ++mt)
    #pragma unroll
    for (int j = 0; j < 4; ++j) {
      int row = mt * 16 + (lane >> 4) * 4 + j;
      #pragma unroll
      for (int nt = 0; nt < 4; ++nt) {
        int col = w * 64 + nt * 16 + (lane & 15);
        float v = fmaxf(acc[mt][nt][j] + by2[col], 0.f)
                  + x[(size_t)(m0 + row) * 256 + col];
        sA[row * 256 + (col ^ ((row & 15) << 3))] = f2bf(v);
      }
    }
  __syncthreads();

  // ---- phase 2: fused F1/F2 over 16 chunks of 64 ----
  f32x4 f2acc[4][4];
  #pragma unroll
  for (int i = 0; i < 4; ++i)
    #pragma unroll
    for (int j = 0; j < 4; ++j) f2acc[i][j] = z4;

  for (int c = 0; c < 1024; c += 64) {
    #pragma unroll
    for (int it = 0; it < 8; ++it) {             // Wf1T chunk [64][256]
      int ch = tid + it * 256;
      int row = ch >> 5, col8 = (ch & 31) * 8;
      u32x4 v = *(const u32x4*)&wf1T[(size_t)(c + row) * 256 + col8];
      *(u32x4*)&sC[row * 256 + (col8 ^ ((row & 15) << 3))] = v;
    }
    __syncthreads();
    f32x4 f1a[4];
    #pragma unroll
    for (int mt = 0; mt < 4; ++mt) f1a[mt] = z4;
    #pragma unroll
    for (int kk8 = 0; kk8 < 8; ++kk8) {
      int k = kk8 * 32 + (lane >> 4) * 8;
      int rb = w * 16 + (lane & 15);
      bf16x8 bgr = *(const bf16x8*)&sC[rb * 256 + (k ^ ((rb & 15) << 3))];
      #pragma unroll
      for (int mt = 0; mt < 4; ++mt) {
        int r = mt * 16 + (lane & 15);
        bf16x8 afr = *(const bf16x8*)&sA[r * 256 + (k ^ ((r & 15) << 3))];
        f1a[mt] = mfma16(afr, bgr, f1a[mt]);
      }
    }
    float b1 = bF1[c + w * 16 + (lane & 15)];
    #pragma unroll
    for (int mt = 0; mt < 4; ++mt)
      #pragma unroll
      for (int j = 0; j < 4; ++j) {
        int row = mt * 16 + (lane >> 4) * 4 + j;
        int col = w * 16 + (lane & 15);
        sF1[row * 64 + (col ^ ((row & 7) << 3))] = f2bf(fmaxf(f1a[mt][j] + b1, 0.f));
      }
    __syncthreads();
    #pragma unroll
    for (int it = 0; it < 8; ++it) {             // Wf2T chunk [256][64]
      int ch = tid + it * 256;
      int row = ch >> 3, col8 = (ch & 7) * 8;
      u32x4 v = *(const u32x4*)&wf2T[(size_t)row * 1024 + c + col8];
      *(u32x4*)&sC[row * 64 + (col8 ^ ((row & 7) << 3))] = v;
    }
    __syncthreads();
    #pragma unroll
    for (int ks = 0; ks < 2; ++ks) {
      int k = ks * 32 + (lane >> 4) * 8;
      bf16x8 af[4], bg[4];
      #pragma unroll
      for (int mt = 0; mt < 4; ++mt) {
        int r = mt * 16 + (lane & 15);
        af[mt] = *(const bf16x8*)&sF1[r * 64 + (k ^ ((r & 7) << 3))];
      }
      #pragma unroll
      for (int nt = 0; nt < 4; ++nt) {
        int r = w * 64 + nt * 16 + (lane & 15);
        bg[nt] = *(const bf16x8*)&sC[r * 64 + (k ^ ((r & 7) << 3))];
      }
      #pragma unroll
      for (int mt = 0; mt < 4; ++mt)
        #pragma unroll
        for (int nt = 0; nt < 4; ++nt)
          f2acc[mt][nt] = mfma16(af[mt], bg[nt], f2acc[mt][nt]);
    }
    __syncthreads();
  }

  // ---- phase 3: bias+relu -> LDS f32, LayerNorm, write Z ----
  #pragma unroll
  for (int mt = 0; mt < 4; ++mt)
    #pragma unroll
    for (int j = 0; j < 4; ++j) {
      int row = mt * 16 + (lane >> 4) * 4 + j;
      #pragma unroll
      for (int nt = 0; nt < 4; ++nt) {
        int col = w * 64 + nt * 16 + (lane & 15);
        F2L[row * 260 + col] = fmaxf(f2acc[mt][nt][j] + bF2[col], 0.f);
      }
    }
  __syncthreads();
  {
    int r = tid >> 2, i4 = tid & 3;
    float s1 = 0.f, s2 = 0.f;
    #pragma unroll 8
    for (int c2 = 0; c2 < 64; ++c2) {
      float v = F2L[r * 260 + i4 * 64 + c2];
      s1 += v; s2 += v * v;
    }
    s1 += __shfl_xor(s1, 1); s2 += __shfl_xor(s2, 1);
    s1 += __shfl_xor(s1, 2); s2 += __shfl_xor(s2, 2);
    if (i4 == 0) {
      float mu = s1 * (1.f / 256.f);
      float var = s2 * (1.f / 256.f) - mu * mu;
      muL[r] = mu;
      rsL[r] = rsqrtf(var + 1e-5f);
    }
  }
  __syncthreads();
  for (int idx = tid; idx < 64 * 256; idx += 256) {
    int r = idx >> 8, cc = idx & 255;
    float v = (F2L[r * 260 + cc] - muL[r]) * rsL[r] * lng[cc] + lnb[cc];
    z[(size_t)(m0 + r) * 256 + cc] = v;
  }
}

// ---------------------------------------------------------------------------
extern "C" void kernel_launch(void* const* d_in, const int* in_sizes, int n_in,
                              void* d_out, int out_size, void* d_ws, size_t ws_size,
                              hipStream_t stream)
{
  const float* x    = (const float*)d_in[0];
  const void*  pmsk = d_in[2];
  const float* W_K  = (const float*)d_in[3];
  const float* b_K  = (const float*)d_in[4];
  const float* W_V  = (const float*)d_in[5];
  const float* b_V  = (const float*)d_in[6];
  const float* W_Q0 = (const float*)d_in[7];
  const float* b_Q0 = (const float*)d_in[8];
  const float* sq   = (const float*)d_in[9];
  const float* W_Y2 = (const float*)d_in[10];
  const float* b_Y2 = (const float*)d_in[11];
  const float* W_F1 = (const float*)d_in[12];
  const float* b_F1 = (const float*)d_in[13];
  const float* W_F2 = (const float*)d_in[14];
  const float* b_F2 = (const float*)d_in[15];
  const float* ln_g = (const float*)d_in[16];
  const float* ln_b = (const float*)d_in[17];

  float* dZ  = (float*)d_out;
  float* dQp = dZ + (size_t)NM * ND;     // 47,710,208
  float* dKp = dQp + (size_t)NM * ND;
  float* dVp = dKp + (size_t)NM * ND;

  char* ws = (char*)d_ws;
  u16* wqkvT = (u16*)(ws);               // 393,216 B
  u16* wy2T  = (u16*)(ws + 393216);      // 131,072 B
  u16* wf1T  = (u16*)(ws + 524288);      // 524,288 B
  u16* wf2T  = (u16*)(ws + 1048576);     // 524,288 B
  u16* y1    = (u16*)(ws + 1572864);     // 95,420,416 B

  hipLaunchKernelGGL(k_prep, dim3(3072), dim3(256), 0, stream,
                     W_K, W_V, W_Q0, W_Y2, W_F1, W_F2, wqkvT, wy2T, wf1T, wf2T);
  hipLaunchKernelGGL(k_qkv, dim3(8736), dim3(256), 0, stream,
                     x, wqkvT, b_K, b_V, b_Q0, sq, dQp, dKp, dVp);
  hipLaunchKernelGGL(k_attn, dim3(8192), dim3(384), 0, stream,
                     dQp, dKp, dVp, pmsk, y1);
  hipLaunchKernelGGL(k_ffn, dim3(2912), dim3(256), 0, stream,
                     y1, x, wy2T, b_Y2, wf1T, b_F1, wf2T, b_F2, ln_g, ln_b, dZ);
}